// Round 8
// baseline (639.600 us; speedup 1.0000x reference)
//
#include <hip/hip_runtime.h>
#include <hip/hip_bf16.h>

#define BB 2
#define CC 512
#define HH 14
#define WW 14
#define PP 196
#define NSEQ 8
#define NSLICE 16                // worker WGs per row (32 ch each)
#define NWORK (14 * NSLICE)      // 224
#define FW 16                    // flag word stride (64B): one line per flag

// ---------------------------------------------------------------------------
// prep: gemm_a (224 WGs) + transpose_wh (256 WGs) + flag zero (1 WG)
// ---------------------------------------------------------------------------
__global__ __launch_bounds__(256) void prep(
    const float* __restrict__ Wx, const float* __restrict__ X,
    const float* __restrict__ b_in, const float* __restrict__ Wh,
    float* __restrict__ A, float* __restrict__ WhT,
    unsigned* __restrict__ flags /* uflag then hflag, contiguous */) {
    __shared__ float Ws[32][33], Xs[32][33];
    int bid = blockIdx.x;
    int t = threadIdx.x;
    if (bid < 224) {
        int z = bid / 112, rem = bid % 112;
        int c0 = (rem % 16) * 32, p0 = (rem / 16) * 32;
        int tx = t % 32, ty = t / 32;
        int pl = (t % 16) * 2, cl = (t / 16) * 2;
        float acc[2][2] = {{0.f,0.f},{0.f,0.f}};
        for (int k0 = 0; k0 < CC; k0 += 32) {
            #pragma unroll
            for (int r = 0; r < 4; ++r)
                Ws[ty + 8*r][tx] = Wx[(size_t)(c0 + ty + 8*r) * CC + k0 + tx];
            #pragma unroll
            for (int r = 0; r < 4; ++r) {
                int p = p0 + tx, k = k0 + ty + 8*r;
                Xs[ty + 8*r][tx] = (p < PP) ? X[((size_t)z * CC + k) * PP + p] : 0.f;
            }
            __syncthreads();
            #pragma unroll
            for (int k = 0; k < 32; ++k) {
                float w0 = Ws[cl][k], w1 = Ws[cl+1][k];
                float x0 = Xs[k][pl], x1 = Xs[k][pl+1];
                acc[0][0] += w0*x0; acc[0][1] += w0*x1;
                acc[1][0] += w1*x0; acc[1][1] += w1*x1;
            }
            __syncthreads();
        }
        #pragma unroll
        for (int i = 0; i < 2; ++i)
            #pragma unroll
            for (int j = 0; j < 2; ++j) {
                int c = c0 + cl + i, p = p0 + pl + j;
                if (p < PP) A[((size_t)z * PP + p) * CC + c] = acc[i][j] + b_in[c];
            }
    } else if (bid < 480) {
        int tid = bid - 224;
        int c0 = (tid % 16) * 32, k0 = (tid / 16) * 32;
        int tx = t % 32, ty = t / 32;
        #pragma unroll
        for (int r = 0; r < 4; ++r)
            Ws[ty + 8*r][tx] = Wh[(size_t)(c0 + ty + 8*r) * CC + k0 + tx];
        __syncthreads();
        #pragma unroll
        for (int r = 0; r < 4; ++r)
            WhT[(size_t)(k0 + ty + 8*r) * CC + c0 + tx] = Ws[tx][ty + 8*r];
    } else {
        for (int i = t; i < (PP*NSLICE + PP*NSEQ) * FW; i += 256) flags[i] = 0u;
    }
}

// ---------------------------------------------------------------------------
// sync primitives
// ---------------------------------------------------------------------------
__device__ __forceinline__ unsigned flag_ld(const unsigned* f) {
    return __hip_atomic_load(f, __ATOMIC_RELAXED, __HIP_MEMORY_SCOPE_AGENT);
}
__device__ __forceinline__ void flag_st(unsigned* f) {
    __hip_atomic_store(f, 1u, __ATOMIC_RELAXED, __HIP_MEMORY_SCOPE_AGENT);
}
__device__ __forceinline__ void store_wt(float* p, float v) {
    __hip_atomic_store(p, v, __ATOMIC_RELAXED, __HIP_MEMORY_SCOPE_AGENT);
}
// wave-level wait for 16 producer words (one per slice), ballot-parallel
__device__ __forceinline__ void wait16(const unsigned* base, int lane) {
    bool ok = false;
    do {
        unsigned f = (lane < 16) ? flag_ld(base + lane * FW) : 1u;
        ok = (__ballot(f != 0u) == ~0ull);
        if (!ok) __builtin_amdgcn_s_sleep(1);
    } while (!ok);
    asm volatile("" ::: "memory");
}

// one window pixel for 8 channels (this wave's seq); E = exp(U) input
__device__ __forceinline__ void pix(const float4 E0, const float4 E1,
                                    const float* ar, const float* er, float* hacc) {
    float ee[8] = {E0.x,E0.y,E0.z,E0.w,E1.x,E1.y,E1.z,E1.w};
    float ds = 0.f, tl[8];
    #pragma unroll
    for (int j = 0; j < 8; ++j) {
        float sv = ar[j] + __logf(ee[j]);
        float pv = er[j] * ee[j];
        ds += fmaxf(pv, 1.0f);
        tl[j] = fmaxf(sv, 0.0f) * pv;
    }
    #pragma unroll
    for (int off = 32; off; off >>= 1) ds += __shfl_xor(ds, off, 64);
    float rd = 1.0f / ds;
    #pragma unroll
    for (int j = 0; j < 8; ++j) hacc[j] += tl[j] * rd;
}

// process n pixels at rowp + y*CC, 4-deep pipelined plain loads
__device__ __forceinline__ void proc_row(const float* __restrict__ rowp, int n,
                                         const float* ar, const float* er, float* hacc) {
    float4 cur[4][2];
    int y = 0, curn = (n < 4) ? n : 4;
    #pragma unroll
    for (int i = 0; i < 4; ++i) if (i < curn) {
        cur[i][0] = *(const float4*)(rowp + (size_t)i * CC);
        cur[i][1] = *(const float4*)(rowp + (size_t)i * CC + 256);
    }
    while (true) {
        int yn = y + curn;
        int rem = n - yn;
        int nextn = (rem < 4) ? rem : 4;
        float4 nxt[4][2];
        #pragma unroll
        for (int i = 0; i < 4; ++i) if (i < nextn) {
            nxt[i][0] = *(const float4*)(rowp + (size_t)(yn + i) * CC);
            nxt[i][1] = *(const float4*)(rowp + (size_t)(yn + i) * CC + 256);
        }
        #pragma unroll
        for (int i = 0; i < 4; ++i) if (i < curn)
            pix(cur[i][0], cur[i][1], ar, er, hacc);
        if (nextn <= 0) break;
        #pragma unroll
        for (int i = 0; i < 4; ++i) if (i < nextn) {
            cur[i][0] = nxt[i][0]; cur[i][1] = nxt[i][1];
        }
        curn = nextn; y = yn;
    }
}

// ---------------------------------------------------------------------------
// One kernel, two roles:
//   blockIdx 0..223   : row workers (row=bid>>4, 32-ch slice). Critical path:
//                       tail (W/N/self softmax) + matvec, ONE crossing/hop.
//   blockIdx 224..419 : per-cell bulk WGs (slack>=2 pixels only), off-path.
// 420 WGs, <=128 VGPR, ~21KB LDS -> 2 WG/CU -> all co-resident by capacity.
// ---------------------------------------------------------------------------
__global__ __launch_bounds__(512, 4) void rnn_dataflow(
    const float* __restrict__ A, const float* __restrict__ WhT,
    float* __restrict__ E, float* __restrict__ h_bulk,
    float* __restrict__ h_t, unsigned* __restrict__ uflag,
    unsigned* __restrict__ hflag) {
    __shared__ float hT[CC * 9];      // h[k][s], stride 9: conflict-free
    __shared__ float red[8][26];      // per-wave ds partials (24 used)
    __shared__ float dsf[26];         // final denominators
    __shared__ float ured[32 * 9];    // matvec result [cl][s], stride 9
    int bid = blockIdx.x;
    int t = threadIdx.x;
    int lane = t & 63, wv = t >> 6;

    if (bid < NWORK) {
        // ================= row worker =================
        int px = bid >> 4, w = bid & 15;
        int ksub = t & 31, quad = t >> 5;
        int c0 = w * 32 + quad * 2;
        float wreg[2][16];
        #pragma unroll
        for (int ci = 0; ci < 2; ++ci)
            #pragma unroll
            for (int j = 0; j < 16; ++j)
                wreg[ci][j] = WhT[(size_t)(ksub + 32*j) * CC + c0 + ci];
        __builtin_amdgcn_s_setprio(1);

        for (int py = 0; py < WW; ++py) {
            int cell = px * WW + py;
            // a / exp(a) for channel c = t, all 8 seqs
            float av[8], er[8];
            #pragma unroll
            for (int s = 0; s < 8; ++s) {
                int m = s >> 1, b = s & 1;
                int fi = (m & 2) ? (HH-1-px) : px, fj = (m & 1) ? (WW-1-py) : py;
                av[s] = A[((size_t)b * PP + fi * WW + fj) * CC + t];
                er[s] = __expf(av[s]);
            }
            // merged poll: lanes 0-7 hbulk, 8-23 North slices, 24-39 West slices
            if (wv == 0) {
                const unsigned* hfB = hflag + (size_t)cell * NSEQ * FW;
                const unsigned* nfB = (px > 0) ?
                    uflag + (size_t)((px-1)*WW + py) * NSLICE * FW : nullptr;
                const unsigned* wfB = (py > 0) ?
                    uflag + (size_t)(px*WW + py-1) * NSLICE * FW : nullptr;
                bool ok = false;
                do {
                    unsigned f = 1u;
                    if (lane < 8)       f = flag_ld(hfB + lane * FW);
                    else if (lane < 24) f = nfB ? flag_ld(nfB + (lane-8)  * FW) : 1u;
                    else if (lane < 40) f = wfB ? flag_ld(wfB + (lane-24) * FW) : 1u;
                    ok = (__ballot(f != 0u) == ~0ull);
                    if (!ok) __builtin_amdgcn_s_sleep(1);
                } while (!ok);
            }
            __syncthreads();
            asm volatile("" ::: "memory");

            // loads: bulk h + North/West full-channel E (channel c = t)
            float hb[8], en[8], ew[8];
            const float* hbB = h_bulk + (size_t)cell * NSEQ * CC;
            #pragma unroll
            for (int s = 0; s < 8; ++s) hb[s] = hbB[(size_t)s * CC + t];
            if (px > 0) {
                int q = (px-1)*WW + py;
                #pragma unroll
                for (int s = 0; s < 8; ++s) en[s] = E[((size_t)s * PP + q) * CC + t];
            }
            if (py > 0) {
                int q = px*WW + py-1;
                #pragma unroll
                for (int s = 0; s < 8; ++s) ew[s] = E[((size_t)s * PP + q) * CC + t];
            }
            // partial denominators: [0..7]=North, [8..15]=West, [16..23]=self
            float pv[24];
            #pragma unroll
            for (int s = 0; s < 8; ++s) {
                pv[s]      = (px > 0) ? fmaxf(er[s]*en[s], 1.f) : 0.f;
                pv[8 + s]  = (py > 0) ? fmaxf(er[s]*ew[s], 1.f) : 0.f;
                pv[16 + s] = fmaxf(er[s], 1.f);
            }
            #pragma unroll
            for (int off = 1; off < 64; off <<= 1)
                #pragma unroll
                for (int i = 0; i < 24; ++i) pv[i] += __shfl_xor(pv[i], off, 64);
            if (lane == 0)
                #pragma unroll
                for (int i = 0; i < 24; ++i) red[wv][i] = pv[i];
            __syncthreads();
            if (t < 24) {
                float x = 0.f;
                #pragma unroll
                for (int r = 0; r < 8; ++r) x += red[r][t];
                dsf[t] = x;
            }
            __syncthreads();
            // assemble full h for channel t and stage for matvec
            #pragma unroll
            for (int s = 0; s < 8; ++s) {
                float h = hb[s] + fmaxf(av[s], 0.f) * er[s] / dsf[16 + s];
                if (px > 0) {
                    float u = __logf(en[s]);
                    h += fmaxf(av[s] + u, 0.f) * (er[s]*en[s]) / dsf[s];
                }
                if (py > 0) {
                    float u = __logf(ew[s]);
                    h += fmaxf(av[s] + u, 0.f) * (er[s]*ew[s]) / dsf[8 + s];
                }
                hT[t * 9 + s] = h;
                if (w == 0) h_t[((size_t)cell * NSEQ + s) * CC + t] = h;
            }
            __syncthreads();
            if (cell == PP - 1) break;       // (13,13): no consumer of U

            // matvec: U_new[c0..c0+1] partial over k = ksub + 32j
            float acc[2][8];
            #pragma unroll
            for (int ci = 0; ci < 2; ++ci)
                #pragma unroll
                for (int ss = 0; ss < 8; ++ss) acc[ci][ss] = 0.f;
            #pragma unroll
            for (int j = 0; j < 16; ++j) {
                int k = ksub + 32*j;
                float hh[8];
                #pragma unroll
                for (int ss = 0; ss < 8; ++ss) hh[ss] = hT[k * 9 + ss];
                #pragma unroll
                for (int ci = 0; ci < 2; ++ci) {
                    float wvv = wreg[ci][j];
                    #pragma unroll
                    for (int ss = 0; ss < 8; ++ss) acc[ci][ss] += wvv * hh[ss];
                }
            }
            #pragma unroll
            for (int off = 1; off < 32; off <<= 1)
                #pragma unroll
                for (int ci = 0; ci < 2; ++ci)
                    #pragma unroll
                    for (int ss = 0; ss < 8; ++ss)
                        acc[ci][ss] += __shfl_xor(acc[ci][ss], off, 64);
            if (ksub == 0)
                #pragma unroll
                for (int ci = 0; ci < 2; ++ci)
                    #pragma unroll
                    for (int ss = 0; ss < 8; ++ss)
                        ured[(quad*2 + ci) * 9 + ss] = acc[ci][ss];
            __syncthreads();
            if (t < 256) {       // publish E = exp(U), coalesced WT stores
                int s = t >> 5, cl = t & 31;
                store_wt(&E[((size_t)s * PP + cell) * CC + w*32 + cl],
                         __expf(ured[cl * 9 + s]));
            }
            __syncthreads();     // all waves' stores drained (vmcnt 0 @ barrier)
            if (t == 0) flag_st(uflag + ((size_t)cell * NSLICE + w) * FW);
        }
    } else {
        // ================= bulk window WG (slack>=2 pixels only) ============
        int cell = bid - NWORK;
        int px = cell / WW, py = cell % WW;
        int s = wv, m = s >> 1, b = s & 1;
        int fi = (m & 2) ? (HH-1-px) : px;
        int fj = (m & 1) ? (WW-1-py) : py;
        int cb = lane * 4;

        const float* acur = A + ((size_t)b * PP + fi * WW + fj) * CC;
        float4 a0 = *(const float4*)(acur + cb);
        float4 a1 = *(const float4*)(acur + cb + 256);
        float ar[8] = {a0.x,a0.y,a0.z,a0.w,a1.x,a1.y,a1.z,a1.w};
        float er[8];
        #pragma unroll
        for (int j = 0; j < 8; ++j) er[j] = __expf(ar[j]);
        float hacc[8] = {0.f,0.f,0.f,0.f,0.f,0.f,0.f,0.f};

        const float* Eb = E + (size_t)s * PP * CC;
        // bulk = rows x<=px-2: y<=py ; row px-1: y<=py-1 ; row px: y<=py-2
        for (int x = 0; x <= px; ++x) {
            int yl = (x <= px-2) ? py : ((x == px-1) ? py-1 : py-2);
            if (yl < 0) continue;
            wait16(uflag + (size_t)(x * WW + yl) * NSLICE * FW, lane);
            proc_row(Eb + (size_t)(x * WW) * CC + cb, yl + 1, ar, er, hacc);
        }
        // publish h_bulk (zeros for empty windows) + per-wave flag
        float* hp = h_bulk + ((size_t)cell * NSEQ + s) * CC;
        #pragma unroll
        for (int j = 0; j < 4; ++j) {
            store_wt(hp + cb + j,       hacc[j]);
            store_wt(hp + cb + 256 + j, hacc[4 + j]);
        }
        __builtin_amdgcn_s_waitcnt(0);
        asm volatile("" ::: "memory");
        if (lane == 0) flag_st(hflag + ((size_t)cell * NSEQ + s) * FW);
    }
}

// ---------------------------------------------------------------------------
// gemm_y: Y[b][p][c] = sum_k Wo[c][k] * (sum_m h_t[p][2m+b][k]) + 4*b_out[c]
// ---------------------------------------------------------------------------
__global__ __launch_bounds__(256) void gemm_y(
    const float* __restrict__ Wo, const float* __restrict__ h_t,
    const float* __restrict__ b_out, float* __restrict__ Y) {
    __shared__ float Ws[32][33], Hs[32][33];
    int b  = blockIdx.z;
    int c0 = blockIdx.x * 32, p0 = blockIdx.y * 32;
    int t  = threadIdx.x;
    int tx = t % 32, ty = t / 32;
    int pl = (t % 16) * 2, cl = (t / 16) * 2;
    float acc[2][2] = {{0.f,0.f},{0.f,0.f}};
    for (int k0 = 0; k0 < CC; k0 += 32) {
        #pragma unroll
        for (int r = 0; r < 4; ++r)
            Ws[ty + 8*r][tx] = Wo[(size_t)(c0 + ty + 8*r) * CC + k0 + tx];
        #pragma unroll
        for (int r = 0; r < 4; ++r) {
            int p = p0 + ty + 8*r;
            float v = 0.f;
            if (p < PP) {
                size_t base = (size_t)p * NSEQ * CC + k0 + tx;
                v = h_t[base + (size_t)(0 + b) * CC]
                  + h_t[base + (size_t)(2 + b) * CC]
                  + h_t[base + (size_t)(4 + b) * CC]
                  + h_t[base + (size_t)(6 + b) * CC];
            }
            Hs[tx][ty + 8*r] = v;
        }
        __syncthreads();
        #pragma unroll
        for (int k = 0; k < 32; ++k) {
            float w0 = Ws[cl][k], w1 = Ws[cl+1][k];
            float h0 = Hs[k][pl], h1 = Hs[k][pl+1];
            acc[0][0] += w0*h0; acc[0][1] += w0*h1;
            acc[1][0] += w1*h0; acc[1][1] += w1*h1;
        }
        __syncthreads();
    }
    #pragma unroll
    for (int i = 0; i < 2; ++i)
        #pragma unroll
        for (int j = 0; j < 2; ++j) {
            int cc = c0 + cl + i, p = p0 + pl + j;
            if (p < PP) Y[((size_t)b * PP + p) * CC + cc] = acc[i][j] + 4.0f * b_out[cc];
        }
}

// ---------------------------------------------------------------------------
// softmax over channels -> out[b][c][p]
// ---------------------------------------------------------------------------
__global__ __launch_bounds__(256) void softmax_out(
    const float* __restrict__ Y, float* __restrict__ out) {
    int wave = threadIdx.x >> 6, lane = threadIdx.x & 63;
    int idx = blockIdx.x * 4 + wave;
    if (idx >= BB * PP) return;
    int b = idx / PP, p = idx % PP;
    const float* y = Y + ((size_t)b * PP + p) * CC;
    float v[8];
    float mx = -3.4e38f;
    #pragma unroll
    for (int j = 0; j < 8; ++j) { v[j] = y[lane + 64*j]; mx = fmaxf(mx, v[j]); }
    #pragma unroll
    for (int off = 32; off; off >>= 1) mx = fmaxf(mx, __shfl_xor(mx, off, 64));
    float sum = 0.f;
    #pragma unroll
    for (int j = 0; j < 8; ++j) { v[j] = expf(v[j] - mx); sum += v[j]; }
    #pragma unroll
    for (int off = 32; off; off >>= 1) sum += __shfl_xor(sum, off, 64);
    float r = 1.0f / sum;
    #pragma unroll
    for (int j = 0; j < 8; ++j)
        out[((size_t)b * CC + lane + 64*j) * PP + p] = v[j] * r;
}

// ---------------------------------------------------------------------------
extern "C" void kernel_launch(void* const* d_in, const int* in_sizes, int n_in,
                              void* d_out, int out_size, void* d_ws, size_t ws_size,
                              hipStream_t stream) {
    const float* X     = (const float*)d_in[0];
    const float* Wx    = (const float*)d_in[1];
    const float* Wh    = (const float*)d_in[2];
    const float* b_in  = (const float*)d_in[3];
    const float* Wo    = (const float*)d_in[4];
    const float* b_out = (const float*)d_in[5];
    float* out = (float*)d_out;

    float* ws     = (float*)d_ws;
    float* WhT    = ws;                     // 262144
    float* A      = WhT    + 262144;        // 200704
    float* E      = A      + 200704;        // 802816  [s][cell][c] = exp(U)
    float* h_bulk = E      + 802816;        // 802816  [cell][s][c]
    float* h_t    = h_bulk + 802816;        // 802816  [cell][s][c] (full h)
    float* Y      = h_t    + 802816;        // 200704
    unsigned* uflag = (unsigned*)(Y + 200704);      // 196*16*FW
    unsigned* hflag = uflag + PP * NSLICE * FW;     // 196*8*FW

    hipLaunchKernelGGL(prep, dim3(481), dim3(256), 0, stream,
                       Wx, X, b_in, Wh, A, WhT, uflag);
    hipLaunchKernelGGL(rnn_dataflow, dim3(NWORK + PP), dim3(512), 0, stream,
                       A, WhT, E, h_bulk, h_t, uflag, hflag);
    hipLaunchKernelGGL(gemm_y, dim3(16, 7, 2), dim3(256), 0, stream, Wo, h_t, b_out, Y);
    hipLaunchKernelGGL(softmax_out, dim3(98), dim3(256), 0, stream, Y, out);
}

// Round 9
// 537.777 us; speedup vs baseline: 1.1893x; 1.1893x over previous
//
#include <hip/hip_runtime.h>
#include <hip/hip_bf16.h>

#define BB 2
#define CC 512
#define HH 14
#define WW 14
#define PP 196
#define NSEQ 8
#define NSLICE 16                // worker WGs per row (32 ch each)
#define NWORK (14 * NSLICE)      // 224
#define FW 16                    // flag words per cell (one 64B line)

// ---------------------------------------------------------------------------
// prep: gemm_a (224 WGs) + transpose_wh (256 WGs) + flag zero (1 WG)
// ---------------------------------------------------------------------------
__global__ __launch_bounds__(256) void prep(
    const float* __restrict__ Wx, const float* __restrict__ X,
    const float* __restrict__ b_in, const float* __restrict__ Wh,
    float* __restrict__ A, float* __restrict__ WhT,
    unsigned* __restrict__ flags /* uflag then hflag, contiguous */) {
    __shared__ float Ws[32][33], Xs[32][33];
    int bid = blockIdx.x;
    int t = threadIdx.x;
    if (bid < 224) {
        int z = bid / 112, rem = bid % 112;
        int c0 = (rem % 16) * 32, p0 = (rem / 16) * 32;
        int tx = t % 32, ty = t / 32;
        int pl = (t % 16) * 2, cl = (t / 16) * 2;
        float acc[2][2] = {{0.f,0.f},{0.f,0.f}};
        for (int k0 = 0; k0 < CC; k0 += 32) {
            #pragma unroll
            for (int r = 0; r < 4; ++r)
                Ws[ty + 8*r][tx] = Wx[(size_t)(c0 + ty + 8*r) * CC + k0 + tx];
            #pragma unroll
            for (int r = 0; r < 4; ++r) {
                int p = p0 + tx, k = k0 + ty + 8*r;
                Xs[ty + 8*r][tx] = (p < PP) ? X[((size_t)z * CC + k) * PP + p] : 0.f;
            }
            __syncthreads();
            #pragma unroll
            for (int k = 0; k < 32; ++k) {
                float w0 = Ws[cl][k], w1 = Ws[cl+1][k];
                float x0 = Xs[k][pl], x1 = Xs[k][pl+1];
                acc[0][0] += w0*x0; acc[0][1] += w0*x1;
                acc[1][0] += w1*x0; acc[1][1] += w1*x1;
            }
            __syncthreads();
        }
        #pragma unroll
        for (int i = 0; i < 2; ++i)
            #pragma unroll
            for (int j = 0; j < 2; ++j) {
                int c = c0 + cl + i, p = p0 + pl + j;
                if (p < PP) A[((size_t)z * PP + p) * CC + c] = acc[i][j] + b_in[c];
            }
    } else if (bid < 480) {
        int tid = bid - 224;
        int c0 = (tid % 16) * 32, k0 = (tid / 16) * 32;
        int tx = t % 32, ty = t / 32;
        #pragma unroll
        for (int r = 0; r < 4; ++r)
            Ws[ty + 8*r][tx] = Wh[(size_t)(c0 + ty + 8*r) * CC + k0 + tx];
        __syncthreads();
        #pragma unroll
        for (int r = 0; r < 4; ++r)
            WhT[(size_t)(k0 + ty + 8*r) * CC + c0 + tx] = Ws[tx][ty + 8*r];
    } else {
        for (int i = t; i < 2 * PP * FW; i += 256) flags[i] = 0u;
    }
}

// ---------------------------------------------------------------------------
// sync primitives
// ---------------------------------------------------------------------------
__device__ __forceinline__ unsigned flag_ld(const unsigned* f) {
    return __hip_atomic_load(f, __ATOMIC_RELAXED, __HIP_MEMORY_SCOPE_AGENT);
}
__device__ __forceinline__ void flag_st(unsigned* f) {
    __hip_atomic_store(f, 1u, __ATOMIC_RELAXED, __HIP_MEMORY_SCOPE_AGENT);
}
__device__ __forceinline__ void store_wt(float* p, float v) {
    __hip_atomic_store(p, v, __ATOMIC_RELAXED, __HIP_MEMORY_SCOPE_AGENT);
}
// check 4 slice flags (pipelined independent loads)
__device__ __forceinline__ bool chk4(const unsigned* fb) {
    unsigned a = flag_ld(fb + 0), b = flag_ld(fb + 1);
    unsigned c = flag_ld(fb + 2), d = flag_ld(fb + 3);
    return (a & b & c & d) != 0u;
}

// one window pixel for 8 channels (this wave's seq); E = exp(U) input
__device__ __forceinline__ void pix(const float4 E0, const float4 E1,
                                    const float* ar, const float* er, float* hacc) {
    float ee[8] = {E0.x,E0.y,E0.z,E0.w,E1.x,E1.y,E1.z,E1.w};
    float ds = 0.f, tl[8];
    #pragma unroll
    for (int j = 0; j < 8; ++j) {
        float sv = ar[j] + __logf(ee[j]);
        float pv = er[j] * ee[j];
        ds += fmaxf(pv, 1.0f);
        tl[j] = fmaxf(sv, 0.0f) * pv;
    }
    #pragma unroll
    for (int off = 32; off; off >>= 1) ds += __shfl_xor(ds, off, 64);
    float rd = 1.0f / ds;
    #pragma unroll
    for (int j = 0; j < 8; ++j) hacc[j] += tl[j] * rd;
}

// process n pixels at rowp + y*CC, 4-deep pipelined plain loads
__device__ __forceinline__ void proc_row(const float* __restrict__ rowp, int n,
                                         const float* ar, const float* er, float* hacc) {
    float4 cur[4][2];
    int y = 0, curn = (n < 4) ? n : 4;
    #pragma unroll
    for (int i = 0; i < 4; ++i) if (i < curn) {
        cur[i][0] = *(const float4*)(rowp + (size_t)i * CC);
        cur[i][1] = *(const float4*)(rowp + (size_t)i * CC + 256);
    }
    while (true) {
        int yn = y + curn;
        int rem = n - yn;
        int nextn = (rem < 4) ? rem : 4;
        float4 nxt[4][2];
        #pragma unroll
        for (int i = 0; i < 4; ++i) if (i < nextn) {
            nxt[i][0] = *(const float4*)(rowp + (size_t)(yn + i) * CC);
            nxt[i][1] = *(const float4*)(rowp + (size_t)(yn + i) * CC + 256);
        }
        #pragma unroll
        for (int i = 0; i < 4; ++i) if (i < curn)
            pix(cur[i][0], cur[i][1], ar, er, hacc);
        if (nextn <= 0) break;
        #pragma unroll
        for (int i = 0; i < 4; ++i) if (i < nextn) {
            cur[i][0] = nxt[i][0]; cur[i][1] = nxt[i][1];
        }
        curn = nextn; y = yn;
    }
}

// ---------------------------------------------------------------------------
// One kernel, two roles:
//   blockIdx 0..223   : persistent matvec workers (row = bid>>4, 32-ch slice)
//   blockIdx 224..419 : per-cell window WGs (wave = seq)
// 420 WGs, <=128 VGPR, ~20KB LDS -> all co-resident by capacity.
// ---------------------------------------------------------------------------
__global__ __launch_bounds__(512, 4) void rnn_dataflow(
    const float* __restrict__ A, const float* __restrict__ WhT,
    float* __restrict__ E, float* __restrict__ h_t,
    unsigned* __restrict__ uflag, unsigned* __restrict__ hflag) {
    __shared__ float smem[CC * 9];    // worker: hT[k][s] stride 9; window: hS[8][512]
    __shared__ float ured[32 * 9];
    int bid = blockIdx.x;
    int t = threadIdx.x;
    int lane = t & 63, wv = t >> 6;

    if (bid < NWORK) {
        // ================= persistent worker =================
        int px = bid >> 4, w = bid & 15;
        int ksub = t & 31, quad = t >> 5;        // 32 k-lanes x 16 c-pairs
        int c0 = w * 32 + quad * 2;
        float wreg[2][16];
        #pragma unroll
        for (int ci = 0; ci < 2; ++ci)
            #pragma unroll
            for (int j = 0; j < 16; ++j)
                wreg[ci][j] = WhT[(size_t)(ksub + 32*j) * CC + c0 + ci];
        __builtin_amdgcn_s_setprio(1);

        for (int py = 0; py < WW; ++py) {
            int cell = px * WW + py;
            if (cell == PP - 1) break;           // (13,13) has no consumer
            if (t == 0) {
                while (flag_ld(hflag + (size_t)cell * FW) == 0u)
                    __builtin_amdgcn_s_sleep(1);
            }
            __syncthreads();
            asm volatile("" ::: "memory");

            // stage h_t[cell][s][k] -> smem[k*9+s] (coalesced loads, CF writes)
            const float* hp = h_t + (size_t)cell * (CC * NSEQ);
            #pragma unroll
            for (int s = 0; s < 8; ++s)
                smem[t * 9 + s] = hp[(size_t)s * CC + t];
            __syncthreads();

            float acc[2][8];
            #pragma unroll
            for (int ci = 0; ci < 2; ++ci)
                #pragma unroll
                for (int ss = 0; ss < 8; ++ss) acc[ci][ss] = 0.f;
            #pragma unroll
            for (int j = 0; j < 16; ++j) {
                int k = ksub + 32*j;
                float hh[8];
                #pragma unroll
                for (int ss = 0; ss < 8; ++ss) hh[ss] = smem[k * 9 + ss];
                #pragma unroll
                for (int ci = 0; ci < 2; ++ci) {
                    float wvv = wreg[ci][j];
                    #pragma unroll
                    for (int ss = 0; ss < 8; ++ss) acc[ci][ss] += wvv * hh[ss];
                }
            }
            #pragma unroll
            for (int off = 1; off < 32; off <<= 1)
                #pragma unroll
                for (int ci = 0; ci < 2; ++ci)
                    #pragma unroll
                    for (int ss = 0; ss < 8; ++ss)
                        acc[ci][ss] += __shfl_xor(acc[ci][ss], off, 64);
            if (ksub == 0)
                #pragma unroll
                for (int ci = 0; ci < 2; ++ci)
                    #pragma unroll
                    for (int ss = 0; ss < 8; ++ss)
                        ured[(quad*2 + ci) * 9 + ss] = acc[ci][ss];
            __syncthreads();
            if (t < 256) {       // publish E = exp(U), coalesced WT dword stores
                int s = t >> 5, cl = t & 31;
                store_wt(&E[((size_t)s * PP + cell) * CC + w*32 + cl],
                         __expf(ured[cl * 9 + s]));
            }
            __syncthreads();     // all waves drained vmcnt before barrier
            if (t == 0) flag_st(uflag + (size_t)cell * FW + w);
        }
    } else {
        // ================= per-cell window WG (wave = seq) ==================
        int cell = bid - NWORK;
        int px = cell / WW, py = cell % WW;
        int s = wv, m = s >> 1, b = s & 1;
        int fi = (m & 2) ? (HH-1-px) : px;
        int fj = (m & 1) ? (WW-1-py) : py;
        int cb = lane * 4;

        const float* acur = A + ((size_t)b * PP + fi * WW + fj) * CC;
        float4 a0 = *(const float4*)(acur + cb);
        float4 a1 = *(const float4*)(acur + cb + 256);
        float ar[8] = {a0.x,a0.y,a0.z,a0.w,a1.x,a1.y,a1.z,a1.w};
        float er[8];
        #pragma unroll
        for (int j = 0; j < 8; ++j) er[j] = __expf(ar[j]);
        float hacc[8] = {0.f,0.f,0.f,0.f,0.f,0.f,0.f,0.f};

        const float* Eb = E + (size_t)s * PP * CC;

        // Phase 1 (slack >= 2): opportunistic rows — poll ALL pending rows in
        // parallel (4 lanes x 4 pipelined flag loads per row), process ready.
        unsigned pend = 0u;
        for (int x = 0; x <= px; ++x) {
            int yl = (x <= px-2) ? py : ((x == px-1) ? py-1 : py-2);
            if (yl >= 0) pend |= (1u << x);
        }
        while (pend) {
            int r = lane >> 2, q = lane & 3;
            bool rdy = true;
            if (r <= px && (pend & (1u << r))) {
                int yl = (r <= px-2) ? py : ((r == px-1) ? py-1 : py-2);
                rdy = chk4(uflag + (size_t)(r * WW + yl) * FW + q * 4);
            }
            unsigned long long bal = __ballot(rdy);
            unsigned newly = 0u, rem2 = pend;
            while (rem2) {
                int x = __ffs(rem2) - 1; rem2 &= rem2 - 1;
                if (((bal >> (4*x)) & 0xFull) == 0xFull) newly |= 1u << x;
            }
            if (!newly) { __builtin_amdgcn_s_sleep(1); continue; }
            asm volatile("" ::: "memory");
            unsigned go = newly;
            while (go) {
                int x = __ffs(go) - 1; go &= go - 1;
                int yl = (x <= px-2) ? py : ((x == px-1) ? py-1 : py-2);
                proc_row(Eb + (size_t)(x * WW) * CC + cb, yl + 1, ar, er, hacc);
            }
            pend &= ~newly;
        }

        // Phase 2: the two d-1 critical pixels, ONE merged poll (max, not sum).
        __builtin_amdgcn_s_setprio(1);
        if (px > 0 || py > 0) {
            int qN = (px-1) * WW + py, qW = px * WW + (py-1);
            while (true) {
                bool rdy = true;
                if (lane < 4) {
                    if (px > 0) rdy = chk4(uflag + (size_t)qN * FW + lane * 4);
                } else if (lane < 8) {
                    if (py > 0) rdy = chk4(uflag + (size_t)qW * FW + (lane-4) * 4);
                }
                if ((__ballot(rdy) & 0xFFull) == 0xFFull) break;
                __builtin_amdgcn_s_sleep(1);
            }
            asm volatile("" ::: "memory");
            if (px > 0) {
                const float4* ep = (const float4*)(Eb + (size_t)qN * CC + cb);
                float4 e0 = ep[0], e1 = ep[64];
                pix(e0, e1, ar, er, hacc);
            }
            if (py > 0) {
                const float4* ep = (const float4*)(Eb + (size_t)qW * CC + cb);
                float4 e0 = ep[0], e1 = ep[64];
                pix(e0, e1, ar, er, hacc);
            }
        }
        {   // self pixel: U=0 -> E=1
            float ds = 0.f, tl[8];
            #pragma unroll
            for (int j = 0; j < 8; ++j) {
                float pv = er[j];
                ds += fmaxf(pv, 1.0f);
                tl[j] = fmaxf(ar[j], 0.0f) * pv;
            }
            #pragma unroll
            for (int off = 32; off; off >>= 1) ds += __shfl_xor(ds, off, 64);
            float rd = 1.0f / ds;
            #pragma unroll
            for (int j = 0; j < 8; ++j) hacc[j] += tl[j] * rd;
        }

        // cooperative coalesced publish: LDS gather -> unit-stride WT stores
        float* hS = smem;                 // [s][c]
        *(float4*)&hS[s * CC + cb]       = make_float4(hacc[0],hacc[1],hacc[2],hacc[3]);
        *(float4*)&hS[s * CC + cb + 256] = make_float4(hacc[4],hacc[5],hacc[6],hacc[7]);
        __syncthreads();
        float* hp = h_t + (size_t)cell * (CC * NSEQ);
        #pragma unroll
        for (int r = 0; r < 8; ++r)
            store_wt(hp + t + 512*r, hS[t + 512*r]);
        __syncthreads();                  // every wave drained vmcnt at barrier
        if (t == 0) flag_st(hflag + (size_t)cell * FW);
    }
}

// ---------------------------------------------------------------------------
// gemm_y: Y[b][p][c] = sum_k Wo[c][k] * (sum_m h_t[p][2m+b][k]) + 4*b_out[c]
// ---------------------------------------------------------------------------
__global__ __launch_bounds__(256) void gemm_y(
    const float* __restrict__ Wo, const float* __restrict__ h_t,
    const float* __restrict__ b_out, float* __restrict__ Y) {
    __shared__ float Ws[32][33], Hs[32][33];
    int b  = blockIdx.z;
    int c0 = blockIdx.x * 32, p0 = blockIdx.y * 32;
    int t  = threadIdx.x;
    int tx = t % 32, ty = t / 32;
    int pl = (t % 16) * 2, cl = (t / 16) * 2;
    float acc[2][2] = {{0.f,0.f},{0.f,0.f}};
    for (int k0 = 0; k0 < CC; k0 += 32) {
        #pragma unroll
        for (int r = 0; r < 4; ++r)
            Ws[ty + 8*r][tx] = Wo[(size_t)(c0 + ty + 8*r) * CC + k0 + tx];
        #pragma unroll
        for (int r = 0; r < 4; ++r) {
            int p = p0 + ty + 8*r;
            float v = 0.f;
            if (p < PP) {
                size_t base = (size_t)p * NSEQ * CC + k0 + tx;
                v = h_t[base + (size_t)(0 + b) * CC]
                  + h_t[base + (size_t)(2 + b) * CC]
                  + h_t[base + (size_t)(4 + b) * CC]
                  + h_t[base + (size_t)(6 + b) * CC];
            }
            Hs[tx][ty + 8*r] = v;
        }
        __syncthreads();
        #pragma unroll
        for (int k = 0; k < 32; ++k) {
            float w0 = Ws[cl][k], w1 = Ws[cl+1][k];
            float h0 = Hs[k][pl], h1 = Hs[k][pl+1];
            acc[0][0] += w0*h0; acc[0][1] += w0*h1;
            acc[1][0] += w1*h0; acc[1][1] += w1*h1;
        }
        __syncthreads();
    }
    #pragma unroll
    for (int i = 0; i < 2; ++i)
        #pragma unroll
        for (int j = 0; j < 2; ++j) {
            int cc = c0 + cl + i, p = p0 + pl + j;
            if (p < PP) Y[((size_t)b * PP + p) * CC + cc] = acc[i][j] + 4.0f * b_out[cc];
        }
}

// ---------------------------------------------------------------------------
// softmax over channels -> out[b][c][p]
// ---------------------------------------------------------------------------
__global__ __launch_bounds__(256) void softmax_out(
    const float* __restrict__ Y, float* __restrict__ out) {
    int wave = threadIdx.x >> 6, lane = threadIdx.x & 63;
    int idx = blockIdx.x * 4 + wave;
    if (idx >= BB * PP) return;
    int b = idx / PP, p = idx % PP;
    const float* y = Y + ((size_t)b * PP + p) * CC;
    float v[8];
    float mx = -3.4e38f;
    #pragma unroll
    for (int j = 0; j < 8; ++j) { v[j] = y[lane + 64*j]; mx = fmaxf(mx, v[j]); }
    #pragma unroll
    for (int off = 32; off; off >>= 1) mx = fmaxf(mx, __shfl_xor(mx, off, 64));
    float sum = 0.f;
    #pragma unroll
    for (int j = 0; j < 8; ++j) { v[j] = expf(v[j] - mx); sum += v[j]; }
    #pragma unroll
    for (int off = 32; off; off >>= 1) sum += __shfl_xor(sum, off, 64);
    float r = 1.0f / sum;
    #pragma unroll
    for (int j = 0; j < 8; ++j)
        out[((size_t)b * CC + lane + 64*j) * PP + p] = v[j] * r;
}

// ---------------------------------------------------------------------------
extern "C" void kernel_launch(void* const* d_in, const int* in_sizes, int n_in,
                              void* d_out, int out_size, void* d_ws, size_t ws_size,
                              hipStream_t stream) {
    const float* X     = (const float*)d_in[0];
    const float* Wx    = (const float*)d_in[1];
    const float* Wh    = (const float*)d_in[2];
    const float* b_in  = (const float*)d_in[3];
    const float* Wo    = (const float*)d_in[4];
    const float* b_out = (const float*)d_in[5];
    float* out = (float*)d_out;

    float* ws  = (float*)d_ws;
    float* WhT = ws;                        // 262144
    float* A   = WhT + 262144;              // 200704
    float* E   = A   + 200704;              // 802816  [s][cell][c] = exp(U)
    float* h_t = E   + 802816;              // 802816  [cell][s][c]
    float* Y   = h_t + 802816;              // 200704
    unsigned* uflag = (unsigned*)(Y + 200704);      // PP*FW
    unsigned* hflag = uflag + PP * FW;              // PP*FW

    hipLaunchKernelGGL(prep, dim3(481), dim3(256), 0, stream,
                       Wx, X, b_in, Wh, A, WhT, uflag);
    hipLaunchKernelGGL(rnn_dataflow, dim3(NWORK + PP), dim3(512), 0, stream,
                       A, WhT, E, h_t, uflag, hflag);
    hipLaunchKernelGGL(gemm_y, dim3(16, 7, 2), dim3(256), 0, stream, Wo, h_t, b_out, Y);
    hipLaunchKernelGGL(softmax_out, dim3(98), dim3(256), 0, stream, Y, out);
}